// Round 10
// baseline (220.882 us; speedup 1.0000x reference)
//
#include <hip/hip_runtime.h>
#include <stdint.h>

#define G_   250
#define P_   200
#define EPG  3200
#define E_   800000
#define F_   128
#define R_   8
#define HROW 136   // f16 elems per row; 272 B stride, 16B-aligned rows
#define NKEY (R_ * P_)   // 1600 (rel,dst) buckets
#define BSET 16384       // f16 elems per (l,r) B-fragment set (32 KB)

typedef _Float16 f16x8 __attribute__((ext_vector_type(8)));
typedef _Float16 f16x4 __attribute__((ext_vector_type(4)));
typedef float    f32x16 __attribute__((ext_vector_type(16)));

// ---------------- prepass: W -> B-fragment layout for mfma_f32_32x32x16_f16 ----------------
// set = l*9+r ; flat = (set*16384) + ((kt*4 + ntj)*64 + lane)*8 + j
// value = W[r][k = kt*16 + (lane>>5)*8 + j][n = ntj*32 + (lane&31)]  (r==8 -> root)
__global__ __launch_bounds__(256) void k_wstage(const float* __restrict__ W1, const float* __restrict__ root1,
                                                const float* __restrict__ W2, const float* __restrict__ root2,
                                                _Float16* __restrict__ wf) {
  int t = blockIdx.x * 256 + threadIdx.x;    // exactly 1152*256 = 2*9*128*128
  int n = t & 127;
  int k = (t >> 7) & 127;
  int rl_ = t >> 14;          // 0..17
  int r = rl_ % 9, l = rl_ / 9;
  const float* Wl = (l == 0) ? W1 : W2;
  const float* rt = (l == 0) ? root1 : root2;
  float v = (r < 8) ? Wl[(r * F_ + k) * F_ + n] : rt[k * F_ + n];
  int lane = (n & 31) | (((k >> 3) & 1) << 5);
  int j = k & 7, kt = k >> 4, ntj = n >> 5;
  wf[(l * 9 + r) * BSET + ((kt * 4 + ntj) * 64 + lane) * 8 + j] = (_Float16)v;
}

// ---------------- main: 1024 threads = 16 waves; 7 m-tiles x 2 n-halves; dbuf B ----------------
__global__ __launch_bounds__(1024) void k_main(
    const float* __restrict__ x, const int* __restrict__ ei, const int* __restrict__ et,
    const _Float16* __restrict__ wf, const float* __restrict__ b1, const float* __restrict__ b2,
    const float* __restrict__ message, const float* __restrict__ embed,
    const float* __restrict__ cw, const float* __restrict__ cb,
    const float* __restrict__ mw, const float* __restrict__ mb,
    float* __restrict__ out) {
  __shared__ __attribute__((aligned(16))) _Float16 hbuf[P_ * HROW];     // 54400 B (x, then h' in place)
  __shared__ __attribute__((aligned(16))) _Float16 Bstage[2][BSET];     // 65536 B
  __shared__ unsigned short csrS[EPG];                                  // 6400 B
  __shared__ int offsS[NKEY + 1];                                       // 6404 B
  __shared__ float msgS[F_ + 1];                                        // 516 B
  __shared__ float scoreS[2 * P_];                                      // 1600 B -> 134856 B

  int g = blockIdx.x, tid = threadIdx.x;
  int lane = tid & 63, wave = tid >> 6;
  int m32 = lane & 31, kh = lane >> 5;

  // ---- early prefetch of B set 0 (consumed at end of setup; flies across all of it) ----
  f16x8 stA = *((const f16x8*)(wf + tid * 8));
  f16x8 stB = *((const f16x8*)(wf + 8192 + tid * 8));

  // ---- setup scratch aliased inside Bstage[1] (first B-write to it is iter 0, post-setup) ----
  int*   Sint = (int*)Bstage[1];
  int*   cnt  = Sint;                    // [1600]
  int*   cur  = Sint + 1600;             // [1600]
  int*   eRec = Sint + 3200;             // [3200]
  float* comb = (float*)(Sint + 6400);   // [256]
  float* red  = (float*)(Sint + 6656);   // [256]  => 27648 B <= 32768 B

  // ---- phase 0: stage x -> hbuf (f16); zero cnt/cur; msg combined features ----
  for (int i = tid; i < P_ * 32; i += 1024) {
    int row = i >> 5, c4 = i & 31;
    const float4 v = ((const float4*)x)[(g * P_ + row) * 32 + c4];
    f16x4 pk = { (_Float16)v.x, (_Float16)v.y, (_Float16)v.z, (_Float16)v.w };
    *((f16x4*)&hbuf[row * HROW + c4 * 4]) = pk;
  }
  for (int i = tid; i < NKEY; i += 1024) { cnt[i] = 0; cur[i] = 0; }
  if (tid < F_) {
    int tok = (int)message[g * 2];
    float cont = message[g * 2 + 1];
    comb[tid] = embed[tok * F_ + tid];
    float ce = cont * cw[tid] + cb[tid];
    comb[F_ + tid] = ce > 0.0f ? ce : 0.0f;
  }
  __syncthreads();

  // ---- phase 1 (wave-specialized): waves 0-11 edge ingest || waves 12-15 msg matmul ----
  int base = g * EPG, nbase = g * P_;
  if (wave < 12) {
    for (int e = wave * 64 + lane; e < EPG; e += 768) {
      int s = ei[base + e] - nbase;
      int d = ei[E_ + base + e] - nbase;
      int r = et[base + e];
      eRec[e] = s | (d << 8) | (r << 16);
      atomicAdd(&cnt[r * P_ + d], 1);
    }
  } else {
    int t2 = tid - 768;            // 0..255
    int col = t2 & 127, seg = t2 >> 7;
    float acc = 0.0f;
#pragma unroll 16
    for (int k2 = seg * 128; k2 < seg * 128 + 128; k2++) acc += comb[k2] * mw[k2 * F_ + col];
    red[t2] = acc;
  }
  __syncthreads();

  // ---- phase 2: wave0 = offset scan (shfl); wave1 = msg finalize ----
  if (wave == 0) {
    int4 vv[8];
    int osum = 0;
    if (lane < 50) {
      const int4* cp = (const int4*)(cnt + lane * 32);
#pragma unroll
      for (int i = 0; i < 8; i++) { vv[i] = cp[i]; osum += vv[i].x + vv[i].y + vv[i].z + vv[i].w; }
    }
    int incl = osum;
#pragma unroll
    for (int d = 1; d < 64; d <<= 1) {
      int t2 = __shfl_up(incl, d, 64);
      if (lane >= d) incl += t2;
    }
    int run = incl - osum;   // exclusive prefix
    if (lane < 50) {
#pragma unroll
      for (int i = 0; i < 8; i++) {
        offsS[lane * 32 + i * 4 + 0] = run; run += vv[i].x;
        offsS[lane * 32 + i * 4 + 1] = run; run += vv[i].y;
        offsS[lane * 32 + i * 4 + 2] = run; run += vv[i].z;
        offsS[lane * 32 + i * 4 + 3] = run; run += vv[i].w;
      }
    }
    if (lane == 0) offsS[NKEY] = EPG;
  } else if (wave == 1) {
    float m0 = mb[lane] + red[lane] + red[128 + lane];
    float m1 = mb[lane + 64] + red[lane + 64] + red[192 + lane];
    m0 = m0 > 0.0f ? m0 : 0.0f;
    m1 = m1 > 0.0f ? m1 : 0.0f;
    msgS[lane] = m0; msgS[lane + 64] = m1;
    float p = m0 * b2[lane] + m1 * b2[lane + 64];
#pragma unroll
    for (int d = 32; d > 0; d >>= 1) p += __shfl_xor(p, d, 64);
    if (lane == 0) msgS[F_] = p;
  }
  __syncthreads();

  // ---- phase 3: CSR scatter from LDS records; then land B(0) into Bstage[0] ----
  for (int e = tid; e < EPG; e += 1024) {
    int rec = eRec[e];
    int s = rec & 255, d = (rec >> 8) & 255, r = rec >> 16;
    int key = r * P_ + d;
    int pos = atomicAdd(&cur[key], 1);
    csrS[offsS[key] + pos] = (unsigned short)s;
  }
  // NOTE: eRec/cur (in Bstage[1]) are dead after this loop; Bstage[0] gets B(0) now.
  *((f16x8*)(&Bstage[0][tid * 8])) = stA;
  *((f16x8*)(&Bstage[0][8192 + tid * 8])) = stB;
  __syncthreads();   // hbuf + csr + offs + msg + B(0) all ready

  // ---- fused layers: flat 18 iterations (l = i/9, r = i%9), one barrier each ----
  int jobId = wave;
  bool act = jobId < 14;
  int mt = jobId >> 1, nh = jobId & 1;     // m-tile 0..6, n-half 0..1
  int rowM = mt * 32 + m32;                // this lane's dst row (may exceed P_-1 on tile 6)
  int ck = kh * 8;
  float db2 = msgS[F_];

  f32x16 acc0, acc1;
#pragma unroll
  for (int i = 0; i < 16; i++) { acc0[i] = 0.0f; acc1[i] = 0.0f; }

  for (int it = 0; it < 18; it++) {
    // prefetch next B set (global, flies across gather+MFMA)
    f16x8 nA, nB;
    if (it < 17) {
      const _Float16* wn = wf + (it + 1) * BSET;
      nA = *((const f16x8*)(wn + tid * 8));
      nB = *((const f16x8*)(wn + 8192 + tid * 8));
    }
    int r = it - (it >= 9 ? 9 : 0);
    const _Float16* Bb = Bstage[it & 1];
    if (act) {
      f16x8 a[8];
      if (r < 8) {
        int o = 0, n = 0;
        if (rowM < P_) { int key = r * P_ + rowM; o = offsS[key]; n = offsS[key + 1] - o; }
        f16x8 z = {0, 0, 0, 0, 0, 0, 0, 0};
#pragma unroll
        for (int kt = 0; kt < 8; kt++) a[kt] = z;
        int t = 0;
        for (; t + 2 <= n; t += 2) {       // unroll-2: 16 reads in flight
          int s0 = (int)csrS[o + t];
          int s1 = (int)csrS[o + t + 1];
          const _Float16* hp0 = &hbuf[s0 * HROW + ck];
          const _Float16* hp1 = &hbuf[s1 * HROW + ck];
          f16x8 u0[8], u1[8];
#pragma unroll
          for (int kt = 0; kt < 8; kt++) u0[kt] = *((const f16x8*)(hp0 + kt * 16));
#pragma unroll
          for (int kt = 0; kt < 8; kt++) u1[kt] = *((const f16x8*)(hp1 + kt * 16));
#pragma unroll
          for (int kt = 0; kt < 8; kt++) a[kt] += u0[kt] + u1[kt];
        }
        if (t < n) {
          int s0 = (int)csrS[o + t];
          const _Float16* hp0 = &hbuf[s0 * HROW + ck];
#pragma unroll
          for (int kt = 0; kt < 8; kt++) a[kt] += *((const f16x8*)(hp0 + kt * 16));
        }
        float nf = (n > 0) ? 1.0f / (float)n : 0.0f;
        _Float16 nh16 = (_Float16)nf;
#pragma unroll
        for (int kt = 0; kt < 8; kt++) a[kt] *= nh16;
      } else {
        int rA = rowM < P_ ? rowM : P_ - 1;
        const _Float16* hp = &hbuf[rA * HROW + ck];
#pragma unroll
        for (int kt = 0; kt < 8; kt++) a[kt] = *((const f16x8*)(hp + kt * 16));
      }
      // MFMA: this wave's n-half (2 nt groups), B from LDS (lane-dense, conflict-free)
#pragma unroll
      for (int kt = 0; kt < 8; kt++) {
        f16x8 b0 = *((const f16x8*)&Bb[((kt * 4 + nh * 2 + 0) * 64 + lane) * 8]);
        acc0 = __builtin_amdgcn_mfma_f32_32x32x16_f16(a[kt], b0, acc0, 0, 0, 0);
        f16x8 b1v = *((const f16x8*)&Bb[((kt * 4 + nh * 2 + 1) * 64 + lane) * 8]);
        acc1 = __builtin_amdgcn_mfma_f32_32x32x16_f16(a[kt], b1v, acc1, 0, 0, 0);
      }
    }
    // land next B set into the other buffer
    if (it < 17) {
      _Float16* Bw = Bstage[(it + 1) & 1];
      *((f16x8*)(&Bw[tid * 8])) = nA;
      *((f16x8*)(&Bw[8192 + tid * 8])) = nB;
    }
    __syncthreads();   // B(it+1) visible; all reads of Bstage[it&1] and hbuf(it) done
    if (it == 8) {
      // layer-1 epilogue: h' = relu(acc + b1) written IN PLACE into hbuf
      if (act) {
#pragma unroll
        for (int nt2 = 0; nt2 < 2; nt2++) {
          int col = (nh * 2 + nt2) * 32 + m32;
          float bias = b1[col];
          const f32x16& ac = nt2 ? acc1 : acc0;
#pragma unroll
          for (int reg = 0; reg < 16; reg++) {
            int row = mt * 32 + (reg & 3) + 8 * (reg >> 2) + 4 * kh;
            if (row < P_) {
              float v = ac[reg] + bias;
              v = v > 0.0f ? v : 0.0f;
              hbuf[row * HROW + col] = (_Float16)v;
            }
          }
        }
      }
      __syncthreads();   // h' complete before layer-2 gathers
#pragma unroll
      for (int i = 0; i < 16; i++) { acc0[i] = 0.0f; acc1[i] = 0.0f; }
    }
  }

  // ---- scoring: dot(node_emb, msg) per row; two n-half partials via scoreS ----
  if (act) {
#pragma unroll
    for (int reg = 0; reg < 16; reg++) {
      int row = mt * 32 + (reg & 3) + 8 * (reg >> 2) + 4 * kh;
      float p = acc0[reg] * msgS[(nh * 2 + 0) * 32 + m32]
              + acc1[reg] * msgS[(nh * 2 + 1) * 32 + m32];
      p += __shfl_xor(p, 16, 32);
      p += __shfl_xor(p, 8, 32);
      p += __shfl_xor(p, 4, 32);
      p += __shfl_xor(p, 2, 32);
      p += __shfl_xor(p, 1, 32);
      if (m32 == 0 && row < P_) scoreS[nh * P_ + row] = p;
    }
  }
  __syncthreads();
  for (int i = tid; i < P_; i += 1024)
    out[g * P_ + i] = scoreS[i] + scoreS[P_ + i] + db2;
}

extern "C" void kernel_launch(void* const* d_in, const int* in_sizes, int n_in,
                              void* d_out, int out_size, void* d_ws, size_t ws_size,
                              hipStream_t stream) {
  const float* message = (const float*)d_in[0];
  const float* x       = (const float*)d_in[1];
  const int*   ei      = (const int*)d_in[2];
  const int*   et      = (const int*)d_in[3];
  const float* W1      = (const float*)d_in[6];
  const float* root1   = (const float*)d_in[7];
  const float* b1      = (const float*)d_in[8];
  const float* W2      = (const float*)d_in[9];
  const float* root2   = (const float*)d_in[10];
  const float* b2      = (const float*)d_in[11];
  const float* embed   = (const float*)d_in[12];
  const float* cw      = (const float*)d_in[13];
  const float* cb      = (const float*)d_in[14];
  const float* mw      = (const float*)d_in[15];
  const float* mb      = (const float*)d_in[16];

  _Float16* wfrag = (_Float16*)d_ws;   // 589,824 B
  float*    out   = (float*)d_out;

  hipLaunchKernelGGL(k_wstage, dim3(1152), dim3(256), 0, stream, W1, root1, W2, root2, wfrag);
  hipLaunchKernelGGL(k_main, dim3(G_), dim3(1024), 0, stream, x, ei, et, wfrag, b1, b2,
                     message, embed, cw, cb, mw, mb, out);
}

// Round 11
// 218.925 us; speedup vs baseline: 1.0089x; 1.0089x over previous
//
#include <hip/hip_runtime.h>
#include <stdint.h>

#define G_   250
#define P_   200
#define EPG  3200
#define E_   800000
#define F_   128
#define R_   8
#define HROW 136   // f16 elems per row; 272 B stride, 16B-aligned rows
#define NKEY (R_ * P_)   // 1600 (rel,dst) buckets
#define BSET 16384       // f16 elems per (l,r) B-fragment set (32 KB)

typedef _Float16 f16x8 __attribute__((ext_vector_type(8)));
typedef _Float16 f16x4 __attribute__((ext_vector_type(4)));
typedef float    f32x16 __attribute__((ext_vector_type(16)));

// ---------------- prepass: W -> B-fragment layout for mfma_f32_32x32x16_f16 ----------------
// set = l*9+r ; flat = (set*16384) + ((kt*4 + ntj)*64 + lane)*8 + j
// value = W[r][k = kt*16 + (lane>>5)*8 + j][n = ntj*32 + (lane&31)]  (r==8 -> root)
__global__ __launch_bounds__(256) void k_wstage(const float* __restrict__ W1, const float* __restrict__ root1,
                                                const float* __restrict__ W2, const float* __restrict__ root2,
                                                _Float16* __restrict__ wf) {
  int t = blockIdx.x * 256 + threadIdx.x;    // exactly 1152*256 = 2*9*128*128
  int n = t & 127;
  int k = (t >> 7) & 127;
  int rl_ = t >> 14;          // 0..17
  int r = rl_ % 9, l = rl_ / 9;
  const float* Wl = (l == 0) ? W1 : W2;
  const float* rt = (l == 0) ? root1 : root2;
  float v = (r < 8) ? Wl[(r * F_ + k) * F_ + n] : rt[k * F_ + n];
  int lane = (n & 31) | (((k >> 3) & 1) << 5);
  int j = k & 7, kt = k >> 4, ntj = n >> 5;
  wf[(l * 9 + r) * BSET + ((kt * 4 + ntj) * 64 + lane) * 8 + j] = (_Float16)v;
}

// ---------------- main: 1024 threads = 16 waves (4/SIMD via launch_bounds); dbuf B ------------
// __launch_bounds__(1024, 4): 4 waves/EU -> 128-VGPR budget. R10's unbounded version let the
// allocator target 64 VGPRs and spill 241 MB of scratch; this is the fix.
__global__ __launch_bounds__(1024, 4) void k_main(
    const float* __restrict__ x, const int* __restrict__ ei, const int* __restrict__ et,
    const _Float16* __restrict__ wf, const float* __restrict__ b1, const float* __restrict__ b2,
    const float* __restrict__ message, const float* __restrict__ embed,
    const float* __restrict__ cw, const float* __restrict__ cb,
    const float* __restrict__ mw, const float* __restrict__ mb,
    float* __restrict__ out) {
  __shared__ __attribute__((aligned(16))) _Float16 hbuf[P_ * HROW];     // 54400 B (x, then h' in place)
  __shared__ __attribute__((aligned(16))) _Float16 Bstage[2][BSET];     // 65536 B
  __shared__ unsigned short csrS[EPG];                                  // 6400 B
  __shared__ int offsS[NKEY + 1];                                       // 6404 B
  __shared__ float msgS[F_ + 1];                                        // 516 B
  __shared__ float scoreS[2 * P_];                                      // 1600 B -> 134856 B

  int g = blockIdx.x, tid = threadIdx.x;
  int lane = tid & 63, wave = tid >> 6;
  int m32 = lane & 31, kh = lane >> 5;

  // ---- early prefetch of B set 0 (consumed at end of setup; flies across all of it) ----
  f16x8 stA = *((const f16x8*)(wf + tid * 8));
  f16x8 stB = *((const f16x8*)(wf + 8192 + tid * 8));

  // ---- setup scratch aliased inside Bstage[1] (first B-write to it is iter 0, post-setup) ----
  int*   Sint = (int*)Bstage[1];
  int*   cnt  = Sint;                    // [1600]
  int*   cur  = Sint + 1600;             // [1600]
  int*   eRec = Sint + 3200;             // [3200]
  float* comb = (float*)(Sint + 6400);   // [256]
  float* red  = (float*)(Sint + 6656);   // [256]  => 27648 B <= 32768 B

  // ---- phase 0: stage x -> hbuf (f16); zero cnt/cur; msg combined features ----
  for (int i = tid; i < P_ * 32; i += 1024) {
    int row = i >> 5, c4 = i & 31;
    const float4 v = ((const float4*)x)[(g * P_ + row) * 32 + c4];
    f16x4 pk = { (_Float16)v.x, (_Float16)v.y, (_Float16)v.z, (_Float16)v.w };
    *((f16x4*)&hbuf[row * HROW + c4 * 4]) = pk;
  }
  for (int i = tid; i < NKEY; i += 1024) { cnt[i] = 0; cur[i] = 0; }
  if (tid < F_) {
    int tok = (int)message[g * 2];
    float cont = message[g * 2 + 1];
    comb[tid] = embed[tok * F_ + tid];
    float ce = cont * cw[tid] + cb[tid];
    comb[F_ + tid] = ce > 0.0f ? ce : 0.0f;
  }
  __syncthreads();

  // ---- phase 1 (wave-specialized): waves 0-11 edge ingest || waves 12-15 msg matmul ----
  int base = g * EPG, nbase = g * P_;
  if (wave < 12) {
    for (int e = wave * 64 + lane; e < EPG; e += 768) {
      int s = ei[base + e] - nbase;
      int d = ei[E_ + base + e] - nbase;
      int r = et[base + e];
      eRec[e] = s | (d << 8) | (r << 16);
      atomicAdd(&cnt[r * P_ + d], 1);
    }
  } else {
    int t2 = tid - 768;            // 0..255
    int col = t2 & 127, seg = t2 >> 7;
    float acc = 0.0f;
#pragma unroll 16
    for (int k2 = seg * 128; k2 < seg * 128 + 128; k2++) acc += comb[k2] * mw[k2 * F_ + col];
    red[t2] = acc;
  }
  __syncthreads();

  // ---- phase 2: wave0 = offset scan (shfl); wave1 = msg finalize ----
  if (wave == 0) {
    int4 vv[8];
    int osum = 0;
    if (lane < 50) {
      const int4* cp = (const int4*)(cnt + lane * 32);
#pragma unroll
      for (int i = 0; i < 8; i++) { vv[i] = cp[i]; osum += vv[i].x + vv[i].y + vv[i].z + vv[i].w; }
    }
    int incl = osum;
#pragma unroll
    for (int d = 1; d < 64; d <<= 1) {
      int t2 = __shfl_up(incl, d, 64);
      if (lane >= d) incl += t2;
    }
    int run = incl - osum;   // exclusive prefix
    if (lane < 50) {
#pragma unroll
      for (int i = 0; i < 8; i++) {
        offsS[lane * 32 + i * 4 + 0] = run; run += vv[i].x;
        offsS[lane * 32 + i * 4 + 1] = run; run += vv[i].y;
        offsS[lane * 32 + i * 4 + 2] = run; run += vv[i].z;
        offsS[lane * 32 + i * 4 + 3] = run; run += vv[i].w;
      }
    }
    if (lane == 0) offsS[NKEY] = EPG;
  } else if (wave == 1) {
    float m0 = mb[lane] + red[lane] + red[128 + lane];
    float m1 = mb[lane + 64] + red[lane + 64] + red[192 + lane];
    m0 = m0 > 0.0f ? m0 : 0.0f;
    m1 = m1 > 0.0f ? m1 : 0.0f;
    msgS[lane] = m0; msgS[lane + 64] = m1;
    float p = m0 * b2[lane] + m1 * b2[lane + 64];
#pragma unroll
    for (int d = 32; d > 0; d >>= 1) p += __shfl_xor(p, d, 64);
    if (lane == 0) msgS[F_] = p;
  }
  __syncthreads();

  // ---- phase 3: CSR scatter from LDS records; then land B(0) into Bstage[0] ----
  for (int e = tid; e < EPG; e += 1024) {
    int rec = eRec[e];
    int s = rec & 255, d = (rec >> 8) & 255, r = rec >> 16;
    int key = r * P_ + d;
    int pos = atomicAdd(&cur[key], 1);
    csrS[offsS[key] + pos] = (unsigned short)s;
  }
  // NOTE: eRec/cur (in Bstage[1]) are dead after this loop; Bstage[0] gets B(0) now.
  *((f16x8*)(&Bstage[0][tid * 8])) = stA;
  *((f16x8*)(&Bstage[0][8192 + tid * 8])) = stB;
  __syncthreads();   // hbuf + csr + offs + msg + B(0) all ready

  // ---- fused layers: flat 18 iterations (l = i/9, r = i%9), one barrier each ----
  int jobId = wave;
  bool act = jobId < 14;
  int mt = jobId >> 1, nh = jobId & 1;     // m-tile 0..6, n-half 0..1
  int rowM = mt * 32 + m32;                // this lane's dst row (may exceed P_-1 on tile 6)
  int ck = kh * 8;
  float db2 = msgS[F_];

  f32x16 acc0, acc1;
#pragma unroll
  for (int i = 0; i < 16; i++) { acc0[i] = 0.0f; acc1[i] = 0.0f; }

  for (int it = 0; it < 18; it++) {
    // prefetch next B set (global, flies across gather+MFMA)
    f16x8 nA, nB;
    if (it < 17) {
      const _Float16* wn = wf + (it + 1) * BSET;
      nA = *((const f16x8*)(wn + tid * 8));
      nB = *((const f16x8*)(wn + 8192 + tid * 8));
    }
    int r = it - (it >= 9 ? 9 : 0);
    const _Float16* Bb = Bstage[it & 1];
    if (act) {
      f16x8 a[8];
      if (r < 8) {
        int o = 0, n = 0;
        if (rowM < P_) { int key = r * P_ + rowM; o = offsS[key]; n = offsS[key + 1] - o; }
        f16x8 z = {0, 0, 0, 0, 0, 0, 0, 0};
#pragma unroll
        for (int kt = 0; kt < 8; kt++) a[kt] = z;
        int t = 0;
        for (; t + 2 <= n; t += 2) {       // unroll-2: 16 reads in flight
          int s0 = (int)csrS[o + t];
          int s1 = (int)csrS[o + t + 1];
          const _Float16* hp0 = &hbuf[s0 * HROW + ck];
          const _Float16* hp1 = &hbuf[s1 * HROW + ck];
          f16x8 u0[8], u1[8];
#pragma unroll
          for (int kt = 0; kt < 8; kt++) u0[kt] = *((const f16x8*)(hp0 + kt * 16));
#pragma unroll
          for (int kt = 0; kt < 8; kt++) u1[kt] = *((const f16x8*)(hp1 + kt * 16));
#pragma unroll
          for (int kt = 0; kt < 8; kt++) a[kt] += u0[kt] + u1[kt];
        }
        if (t < n) {
          int s0 = (int)csrS[o + t];
          const _Float16* hp0 = &hbuf[s0 * HROW + ck];
#pragma unroll
          for (int kt = 0; kt < 8; kt++) a[kt] += *((const f16x8*)(hp0 + kt * 16));
        }
        float nf = (n > 0) ? 1.0f / (float)n : 0.0f;
        _Float16 nh16 = (_Float16)nf;
#pragma unroll
        for (int kt = 0; kt < 8; kt++) a[kt] *= nh16;
      } else {
        int rA = rowM < P_ ? rowM : P_ - 1;
        const _Float16* hp = &hbuf[rA * HROW + ck];
#pragma unroll
        for (int kt = 0; kt < 8; kt++) a[kt] = *((const f16x8*)(hp + kt * 16));
      }
      // MFMA: this wave's n-half (2 nt groups), B from LDS (lane-dense, conflict-free)
#pragma unroll
      for (int kt = 0; kt < 8; kt++) {
        f16x8 b0 = *((const f16x8*)&Bb[((kt * 4 + nh * 2 + 0) * 64 + lane) * 8]);
        acc0 = __builtin_amdgcn_mfma_f32_32x32x16_f16(a[kt], b0, acc0, 0, 0, 0);
        f16x8 b1v = *((const f16x8*)&Bb[((kt * 4 + nh * 2 + 1) * 64 + lane) * 8]);
        acc1 = __builtin_amdgcn_mfma_f32_32x32x16_f16(a[kt], b1v, acc1, 0, 0, 0);
      }
    }
    // land next B set into the other buffer
    if (it < 17) {
      _Float16* Bw = Bstage[(it + 1) & 1];
      *((f16x8*)(&Bw[tid * 8])) = nA;
      *((f16x8*)(&Bw[8192 + tid * 8])) = nB;
    }
    __syncthreads();   // B(it+1) visible; all reads of Bstage[it&1] and hbuf(it) done
    if (it == 8) {
      // layer-1 epilogue: h' = relu(acc + b1) written IN PLACE into hbuf
      if (act) {
#pragma unroll
        for (int nt2 = 0; nt2 < 2; nt2++) {
          int col = (nh * 2 + nt2) * 32 + m32;
          float bias = b1[col];
          const f32x16& ac = nt2 ? acc1 : acc0;
#pragma unroll
          for (int reg = 0; reg < 16; reg++) {
            int row = mt * 32 + (reg & 3) + 8 * (reg >> 2) + 4 * kh;
            if (row < P_) {
              float v = ac[reg] + bias;
              v = v > 0.0f ? v : 0.0f;
              hbuf[row * HROW + col] = (_Float16)v;
            }
          }
        }
      }
      __syncthreads();   // h' complete before layer-2 gathers
#pragma unroll
      for (int i = 0; i < 16; i++) { acc0[i] = 0.0f; acc1[i] = 0.0f; }
    }
  }

  // ---- scoring: dot(node_emb, msg) per row; two n-half partials via scoreS ----
  if (act) {
#pragma unroll
    for (int reg = 0; reg < 16; reg++) {
      int row = mt * 32 + (reg & 3) + 8 * (reg >> 2) + 4 * kh;
      float p = acc0[reg] * msgS[(nh * 2 + 0) * 32 + m32]
              + acc1[reg] * msgS[(nh * 2 + 1) * 32 + m32];
      p += __shfl_xor(p, 16, 32);
      p += __shfl_xor(p, 8, 32);
      p += __shfl_xor(p, 4, 32);
      p += __shfl_xor(p, 2, 32);
      p += __shfl_xor(p, 1, 32);
      if (m32 == 0 && row < P_) scoreS[nh * P_ + row] = p;
    }
  }
  __syncthreads();
  for (int i = tid; i < P_; i += 1024)
    out[g * P_ + i] = scoreS[i] + scoreS[P_ + i] + db2;
}

extern "C" void kernel_launch(void* const* d_in, const int* in_sizes, int n_in,
                              void* d_out, int out_size, void* d_ws, size_t ws_size,
                              hipStream_t stream) {
  const float* message = (const float*)d_in[0];
  const float* x       = (const float*)d_in[1];
  const int*   ei      = (const int*)d_in[2];
  const int*   et      = (const int*)d_in[3];
  const float* W1      = (const float*)d_in[6];
  const float* root1   = (const float*)d_in[7];
  const float* b1      = (const float*)d_in[8];
  const float* W2      = (const float*)d_in[9];
  const float* root2   = (const float*)d_in[10];
  const float* b2      = (const float*)d_in[11];
  const float* embed   = (const float*)d_in[12];
  const float* cw      = (const float*)d_in[13];
  const float* cb      = (const float*)d_in[14];
  const float* mw      = (const float*)d_in[15];
  const float* mb      = (const float*)d_in[16];

  _Float16* wfrag = (_Float16*)d_ws;   // 589,824 B
  float*    out   = (float*)d_out;

  hipLaunchKernelGGL(k_wstage, dim3(1152), dim3(256), 0, stream, W1, root1, W2, root2, wfrag);
  hipLaunchKernelGGL(k_main, dim3(G_), dim3(1024), 0, stream, x, ei, et, wfrag, b1, b2,
                     message, embed, cw, cb, mw, mb, out);
}

// Round 12
// 181.616 us; speedup vs baseline: 1.2162x; 1.2054x over previous
//
#include <hip/hip_runtime.h>
#include <stdint.h>

#define G_   250
#define P_   200
#define EPG  3200
#define E_   800000
#define F_   128
#define R_   8
#define HROW 136   // f16 elems per row; 272 B stride, 16B-aligned rows
#define NKEY (R_ * P_)   // 1600 (rel,dst) buckets
#define BSET 16384       // f16 elems per (l,r) B-fragment set (32 KB)

typedef _Float16 f16x8 __attribute__((ext_vector_type(8)));
typedef _Float16 f16x4 __attribute__((ext_vector_type(4)));
typedef float    f32x16 __attribute__((ext_vector_type(16)));

// ---------------- prepass: W -> B-fragment layout for mfma_f32_32x32x16_f16 ----------------
// set = l*9+r ; flat = (set*16384) + ((kt*4 + ntj)*64 + lane)*8 + j
// value = W[r][k = kt*16 + (lane>>5)*8 + j][n = ntj*32 + (lane&31)]  (r==8 -> root)
__global__ __launch_bounds__(256) void k_wstage(const float* __restrict__ W1, const float* __restrict__ root1,
                                                const float* __restrict__ W2, const float* __restrict__ root2,
                                                _Float16* __restrict__ wf) {
  int t = blockIdx.x * 256 + threadIdx.x;    // exactly 1152*256 = 2*9*128*128
  int n = t & 127;
  int k = (t >> 7) & 127;
  int rl_ = t >> 14;          // 0..17
  int r = rl_ % 9, l = rl_ / 9;
  const float* Wl = (l == 0) ? W1 : W2;
  const float* rt = (l == 0) ? root1 : root2;
  float v = (r < 8) ? Wl[(r * F_ + k) * F_ + n] : rt[k * F_ + n];
  int lane = (n & 31) | (((k >> 3) & 1) << 5);
  int j = k & 7, kt = k >> 4, ntj = n >> 5;
  wf[(l * 9 + r) * BSET + ((kt * 4 + ntj) * 64 + lane) * 8 + j] = (_Float16)v;
}

// ---------------- main: 1024 threads = 16 waves; amdgpu_waves_per_eu(4,4) pins the
// allocator's occupancy target at exactly 4 waves/EU (128-VGPR budget). launch_bounds'
// min-waves arg alone let the heuristic target 8 waves (64 VGPR) and spill 241 MB (R10/R11).
__global__ __launch_bounds__(1024) __attribute__((amdgpu_waves_per_eu(4, 4))) void k_main(
    const float* __restrict__ x, const int* __restrict__ ei, const int* __restrict__ et,
    const _Float16* __restrict__ wf, const float* __restrict__ b1, const float* __restrict__ b2,
    const float* __restrict__ message, const float* __restrict__ embed,
    const float* __restrict__ cw, const float* __restrict__ cb,
    const float* __restrict__ mw, const float* __restrict__ mb,
    float* __restrict__ out) {
  __shared__ __attribute__((aligned(16))) _Float16 hbuf[P_ * HROW];     // 54400 B (x, then h' in place)
  __shared__ __attribute__((aligned(16))) _Float16 Bstage[2][BSET];     // 65536 B
  __shared__ unsigned short csrS[EPG];                                  // 6400 B
  __shared__ int offsS[NKEY + 1];                                       // 6404 B
  __shared__ float msgS[F_ + 1];                                        // 516 B
  __shared__ float scoreS[2 * P_];                                      // 1600 B -> 134856 B

  int g = blockIdx.x, tid = threadIdx.x;
  int lane = tid & 63, wave = tid >> 6;
  int m32 = lane & 31, kh = lane >> 5;

  // ---- early prefetch of B set 0 (consumed at end of setup; flies across all of it) ----
  f16x8 stA = *((const f16x8*)(wf + tid * 8));
  f16x8 stB = *((const f16x8*)(wf + 8192 + tid * 8));

  // ---- setup scratch aliased inside Bstage[1] (first B-write to it is iter 0, post-setup) ----
  int*   Sint = (int*)Bstage[1];
  int*   cnt  = Sint;                    // [1600]
  int*   cur  = Sint + 1600;             // [1600]
  int*   eRec = Sint + 3200;             // [3200]
  float* comb = (float*)(Sint + 6400);   // [256]
  float* red  = (float*)(Sint + 6656);   // [256]  => 27648 B <= 32768 B

  // ---- phase 0: stage x -> hbuf (f16); zero cnt/cur; msg combined features ----
  for (int i = tid; i < P_ * 32; i += 1024) {
    int row = i >> 5, c4 = i & 31;
    const float4 v = ((const float4*)x)[(g * P_ + row) * 32 + c4];
    f16x4 pk = { (_Float16)v.x, (_Float16)v.y, (_Float16)v.z, (_Float16)v.w };
    *((f16x4*)&hbuf[row * HROW + c4 * 4]) = pk;
  }
  for (int i = tid; i < NKEY; i += 1024) { cnt[i] = 0; cur[i] = 0; }
  if (tid < F_) {
    int tok = (int)message[g * 2];
    float cont = message[g * 2 + 1];
    comb[tid] = embed[tok * F_ + tid];
    float ce = cont * cw[tid] + cb[tid];
    comb[F_ + tid] = ce > 0.0f ? ce : 0.0f;
  }
  __syncthreads();

  // ---- phase 1 (wave-specialized): waves 0-11 edge ingest || waves 12-15 msg matmul ----
  int base = g * EPG, nbase = g * P_;
  if (wave < 12) {
    for (int e = wave * 64 + lane; e < EPG; e += 768) {
      int s = ei[base + e] - nbase;
      int d = ei[E_ + base + e] - nbase;
      int r = et[base + e];
      eRec[e] = s | (d << 8) | (r << 16);
      atomicAdd(&cnt[r * P_ + d], 1);
    }
  } else {
    int t2 = tid - 768;            // 0..255
    int col = t2 & 127, seg = t2 >> 7;
    float acc = 0.0f;
#pragma unroll 16
    for (int k2 = seg * 128; k2 < seg * 128 + 128; k2++) acc += comb[k2] * mw[k2 * F_ + col];
    red[t2] = acc;
  }
  __syncthreads();

  // ---- phase 2: wave0 = offset scan (shfl); wave1 = msg finalize ----
  if (wave == 0) {
    int4 vv[8];
    int osum = 0;
    if (lane < 50) {
      const int4* cp = (const int4*)(cnt + lane * 32);
#pragma unroll
      for (int i = 0; i < 8; i++) { vv[i] = cp[i]; osum += vv[i].x + vv[i].y + vv[i].z + vv[i].w; }
    }
    int incl = osum;
#pragma unroll
    for (int d = 1; d < 64; d <<= 1) {
      int t2 = __shfl_up(incl, d, 64);
      if (lane >= d) incl += t2;
    }
    int run = incl - osum;   // exclusive prefix
    if (lane < 50) {
#pragma unroll
      for (int i = 0; i < 8; i++) {
        offsS[lane * 32 + i * 4 + 0] = run; run += vv[i].x;
        offsS[lane * 32 + i * 4 + 1] = run; run += vv[i].y;
        offsS[lane * 32 + i * 4 + 2] = run; run += vv[i].z;
        offsS[lane * 32 + i * 4 + 3] = run; run += vv[i].w;
      }
    }
    if (lane == 0) offsS[NKEY] = EPG;
  } else if (wave == 1) {
    float m0 = mb[lane] + red[lane] + red[128 + lane];
    float m1 = mb[lane + 64] + red[lane + 64] + red[192 + lane];
    m0 = m0 > 0.0f ? m0 : 0.0f;
    m1 = m1 > 0.0f ? m1 : 0.0f;
    msgS[lane] = m0; msgS[lane + 64] = m1;
    float p = m0 * b2[lane] + m1 * b2[lane + 64];
#pragma unroll
    for (int d = 32; d > 0; d >>= 1) p += __shfl_xor(p, d, 64);
    if (lane == 0) msgS[F_] = p;
  }
  __syncthreads();

  // ---- phase 3: CSR scatter from LDS records; then land B(0) into Bstage[0] ----
  for (int e = tid; e < EPG; e += 1024) {
    int rec = eRec[e];
    int s = rec & 255, d = (rec >> 8) & 255, r = rec >> 16;
    int key = r * P_ + d;
    int pos = atomicAdd(&cur[key], 1);
    csrS[offsS[key] + pos] = (unsigned short)s;
  }
  // NOTE: eRec/cur (in Bstage[1]) are dead after this loop; Bstage[0] gets B(0) now.
  *((f16x8*)(&Bstage[0][tid * 8])) = stA;
  *((f16x8*)(&Bstage[0][8192 + tid * 8])) = stB;
  __syncthreads();   // hbuf + csr + offs + msg + B(0) all ready

  // ---- fused layers: flat 18 iterations (l = i/9, r = i%9), one barrier each ----
  int jobId = wave;
  bool act = jobId < 14;
  int mt = jobId >> 1, nh = jobId & 1;     // m-tile 0..6, n-half 0..1
  int rowM = mt * 32 + m32;                // this lane's dst row (may exceed P_-1 on tile 6)
  int ck = kh * 8;
  float db2 = msgS[F_];

  f32x16 acc0, acc1;
#pragma unroll
  for (int i = 0; i < 16; i++) { acc0[i] = 0.0f; acc1[i] = 0.0f; }

  for (int it = 0; it < 18; it++) {
    // prefetch next B set (global, flies across gather+MFMA)
    f16x8 nA, nB;
    if (it < 17) {
      const _Float16* wn = wf + (it + 1) * BSET;
      nA = *((const f16x8*)(wn + tid * 8));
      nB = *((const f16x8*)(wn + 8192 + tid * 8));
    }
    int r = it - (it >= 9 ? 9 : 0);
    const _Float16* Bb = Bstage[it & 1];
    if (act) {
      f16x8 a[8];
      if (r < 8) {
        int o = 0, n = 0;
        if (rowM < P_) { int key = r * P_ + rowM; o = offsS[key]; n = offsS[key + 1] - o; }
        f16x8 z = {0, 0, 0, 0, 0, 0, 0, 0};
#pragma unroll
        for (int kt = 0; kt < 8; kt++) a[kt] = z;
        // single-chain gather: 8 independent b128 reads per edge; TLP (4 waves/SIMD)
        // hides the dependent-add latency. (unroll-2 temps dropped to fit 128 VGPRs.)
        for (int t = 0; t < n; t++) {
          int sc = (int)csrS[o + t];
          const _Float16* hp = &hbuf[sc * HROW + ck];
#pragma unroll
          for (int kt = 0; kt < 8; kt++) a[kt] += *((const f16x8*)(hp + kt * 16));
        }
        float nf = (n > 0) ? 1.0f / (float)n : 0.0f;
        _Float16 nh16 = (_Float16)nf;
#pragma unroll
        for (int kt = 0; kt < 8; kt++) a[kt] *= nh16;
      } else {
        int rA = rowM < P_ ? rowM : P_ - 1;
        const _Float16* hp = &hbuf[rA * HROW + ck];
#pragma unroll
        for (int kt = 0; kt < 8; kt++) a[kt] = *((const f16x8*)(hp + kt * 16));
      }
      // MFMA: this wave's n-half (2 nt groups), B from LDS (lane-dense, conflict-free)
#pragma unroll
      for (int kt = 0; kt < 8; kt++) {
        f16x8 b0 = *((const f16x8*)&Bb[((kt * 4 + nh * 2 + 0) * 64 + lane) * 8]);
        acc0 = __builtin_amdgcn_mfma_f32_32x32x16_f16(a[kt], b0, acc0, 0, 0, 0);
        f16x8 b1v = *((const f16x8*)&Bb[((kt * 4 + nh * 2 + 1) * 64 + lane) * 8]);
        acc1 = __builtin_amdgcn_mfma_f32_32x32x16_f16(a[kt], b1v, acc1, 0, 0, 0);
      }
    }
    // land next B set into the other buffer
    if (it < 17) {
      _Float16* Bw = Bstage[(it + 1) & 1];
      *((f16x8*)(&Bw[tid * 8])) = nA;
      *((f16x8*)(&Bw[8192 + tid * 8])) = nB;
    }
    __syncthreads();   // B(it+1) visible; all reads of Bstage[it&1] and hbuf(it) done
    if (it == 8) {
      // layer-1 epilogue: h' = relu(acc + b1) written IN PLACE into hbuf
      if (act) {
#pragma unroll
        for (int nt2 = 0; nt2 < 2; nt2++) {
          int col = (nh * 2 + nt2) * 32 + m32;
          float bias = b1[col];
          const f32x16& ac = nt2 ? acc1 : acc0;
#pragma unroll
          for (int reg = 0; reg < 16; reg++) {
            int row = mt * 32 + (reg & 3) + 8 * (reg >> 2) + 4 * kh;
            if (row < P_) {
              float v = ac[reg] + bias;
              v = v > 0.0f ? v : 0.0f;
              hbuf[row * HROW + col] = (_Float16)v;
            }
          }
        }
      }
      __syncthreads();   // h' complete before layer-2 gathers
#pragma unroll
      for (int i = 0; i < 16; i++) { acc0[i] = 0.0f; acc1[i] = 0.0f; }
    }
  }

  // ---- scoring: dot(node_emb, msg) per row; two n-half partials via scoreS ----
  if (act) {
#pragma unroll
    for (int reg = 0; reg < 16; reg++) {
      int row = mt * 32 + (reg & 3) + 8 * (reg >> 2) + 4 * kh;
      float p = acc0[reg] * msgS[(nh * 2 + 0) * 32 + m32]
              + acc1[reg] * msgS[(nh * 2 + 1) * 32 + m32];
      p += __shfl_xor(p, 16, 32);
      p += __shfl_xor(p, 8, 32);
      p += __shfl_xor(p, 4, 32);
      p += __shfl_xor(p, 2, 32);
      p += __shfl_xor(p, 1, 32);
      if (m32 == 0 && row < P_) scoreS[nh * P_ + row] = p;
    }
  }
  __syncthreads();
  for (int i = tid; i < P_; i += 1024)
    out[g * P_ + i] = scoreS[i] + scoreS[P_ + i] + db2;
}

extern "C" void kernel_launch(void* const* d_in, const int* in_sizes, int n_in,
                              void* d_out, int out_size, void* d_ws, size_t ws_size,
                              hipStream_t stream) {
  const float* message = (const float*)d_in[0];
  const float* x       = (const float*)d_in[1];
  const int*   ei      = (const int*)d_in[2];
  const int*   et      = (const int*)d_in[3];
  const float* W1      = (const float*)d_in[6];
  const float* root1   = (const float*)d_in[7];
  const float* b1      = (const float*)d_in[8];
  const float* W2      = (const float*)d_in[9];
  const float* root2   = (const float*)d_in[10];
  const float* b2      = (const float*)d_in[11];
  const float* embed   = (const float*)d_in[12];
  const float* cw      = (const float*)d_in[13];
  const float* cb      = (const float*)d_in[14];
  const float* mw      = (const float*)d_in[15];
  const float* mb      = (const float*)d_in[16];

  _Float16* wfrag = (_Float16*)d_ws;   // 589,824 B
  float*    out   = (float*)d_out;

  hipLaunchKernelGGL(k_wstage, dim3(1152), dim3(256), 0, stream, W1, root1, W2, root2, wfrag);
  hipLaunchKernelGGL(k_main, dim3(G_), dim3(1024), 0, stream, x, ei, et, wfrag, b1, b2,
                     message, embed, cw, cb, mw, mb, out);
}